// Round 10
// baseline (765.092 us; speedup 1.0000x reference)
//
#include <hip/hip_runtime.h>
#include <math.h>

#define HIDDEN  2048
#define NEXP    256
#define TOPK    8
#define NGROUP  8
#define TKG     4
#define GSZ     32
#define TM      32                 // tokens per block
#define KC      32                 // k-chunk (two 16-elem SSE groups)
#define NCHUNK  (HIDDEN / KC)      // 64
#define LGSTR   (NEXP + 2)         // logits row stride in pool

// Bit-exact emulation of numpy c_einsum's f32 dot kernel (SSE baseline):
//   - 4 lane-chains (k mod 4), mul/add separately rounded (no FMA)
//   - 16-elem groups ascending; within a group float4s accumulated reversed
//   - final combine (A0+A1)+(A2+A3)
// Numerics/op-order identical to the r3 passing kernel. Change vs r3:
// X is NOT staged in LDS; the wave-uniform xv float4 is read directly from
// global (64-lane same-address load -> one L1 transaction on the idle VMEM
// pipe). This removes 256 of the 384 ds_read_b128 per chunk per block --
// the LDS pipe was the measured wall (r3/r5 both ~500us at equal LDS totals).
// Register law (r4/r6/r7/r8/r9): only transient staging regs, (256,2).
__global__ __launch_bounds__(256, 2) void moe_gate_main(
    const float* __restrict__ X,      // [T, HIDDEN]
    const float* __restrict__ W,      // [NEXP, HIDDEN]
    float* __restrict__ out,          // [T*8 idx][T*8 w][1 loss]
    double* __restrict__ S_ws,        // [NEXP]
    int* __restrict__ cnt_ws,         // [NEXP]
    int T)
{
#pragma clang fp contract(off)
    __shared__ __align__(16) float pool[TM * LGSTR];    // 33 KB: W tile during GEMM, logits after
    __shared__ float dmax[TM];
    __shared__ float den[TM];

    const int tid = threadIdx.x;
    const int tg  = tid >> 6;        // wave id -> token octet (wave-uniform)
    const int exq = tid & 63;        // expert base lane
    const int t0  = blockIdx.x * TM;
    const int swz = exq & 7;

    // 32-bit element offsets of this wave's 8 token rows (values wave-uniform)
    int xoff[8];
#pragma unroll
    for (int i = 0; i < 8; ++i) xoff[i] = (t0 + tg * 8 + i) * HIDDEN;

    float4 acc[8][4];                // [token][expert-quad], 128 floats
#pragma unroll
    for (int i = 0; i < 8; ++i)
#pragma unroll
        for (int j = 0; j < 4; ++j) acc[i][j] = make_float4(0.f, 0.f, 0.f, 0.f);

    for (int c = 0; c < NCHUNK; ++c) {
        const int k0 = c * KC;
        __syncthreads();                 // previous chunk's W tile fully consumed
        // stage W chunk [256 experts][32 k]: 8 float4 per thread (transient batch,
        // proven to fit the 128-VGPR envelope), XOR-swizzled 16B columns
#pragma unroll
        for (int it = 0; it < 8; ++it) {
            const int f4  = it * 256 + tid;
            const int row = f4 >> 3, col4 = f4 & 7;
            const float4 v = *(const float4*)(W + (size_t)row * HIDDEN + k0 + 4 * col4);
            *(float4*)&pool[row * KC + ((col4 ^ (row & 7)) * 4)] = v;
        }
        __syncthreads();
        // two 16-elem groups, vectors reversed within each (SSE chain order)
#pragma unroll
        for (int blk = 0; blk < 2; ++blk) {
#pragma unroll
            for (int vv = 3; vv >= 0; --vv) {
                const int k4 = blk * 4 + vv;
                const int sc = (k4 ^ swz) * 4;
                float4 wv[4];
#pragma unroll
                for (int j = 0; j < 4; ++j)
                    wv[j] = *(const float4*)&pool[(exq + 64 * j) * KC + sc];
#pragma unroll
                for (int i = 0; i < 8; ++i) {
                    // wave-uniform address: 64-lane broadcast, single L1 16B fetch
                    const float4 xv = *(const float4*)(X + xoff[i] + k0 + 4 * k4);
#pragma unroll
                    for (int j = 0; j < 4; ++j) {
                        // ascending k within each mod-4 chain -- DO NOT reorder
                        acc[i][j].x = __fadd_rn(acc[i][j].x, __fmul_rn(xv.x, wv[j].x));
                        acc[i][j].y = __fadd_rn(acc[i][j].y, __fmul_rn(xv.y, wv[j].y));
                        acc[i][j].z = __fadd_rn(acc[i][j].z, __fmul_rn(xv.z, wv[j].z));
                        acc[i][j].w = __fadd_rn(acc[i][j].w, __fmul_rn(xv.w, wv[j].w));
                    }
                }
            }
        }
    }

    __syncthreads();   // all W-tile reads done; pool becomes the logits buffer
#pragma unroll
    for (int i = 0; i < 8; ++i)
#pragma unroll
        for (int j = 0; j < 4; ++j) {
            const float4 a = acc[i][j];
            // SSE3 hadd x2: (A0+A1)+(A2+A3)
            pool[(tg * 8 + i) * LGSTR + exq + 64 * j] =
                __fadd_rn(__fadd_rn(a.x, a.y), __fadd_rn(a.z, a.w));
        }
    __syncthreads();

    // ---- per-token selection: grouped top-4, global top-8, softmax weights ----
    if (tid < TM) {
        const int t = tid;
        float cv[NGROUP * TKG];
        int   ci[NGROUP * TKG];
        float gmax = -3.0e38f;

        for (int g = 0; g < NGROUP; ++g) {
            float v4[TKG] = { -3.0e38f, -3.0e38f, -3.0e38f, -3.0e38f };
            int   i4[TKG] = { 0, 0, 0, 0 };
            for (int jj = 0; jj < GSZ; ++jj) {
                const float v = pool[t * LGSTR + g * GSZ + jj];
                if (v > gmax) gmax = v;
                if (v > v4[TKG - 1]) {          // strict > : stable (lower idx first)
                    int q = TKG - 1;
                    while (q > 0 && v > v4[q - 1]) {
                        v4[q] = v4[q - 1]; i4[q] = i4[q - 1]; --q;
                    }
                    v4[q] = v; i4[q] = jj;
                }
            }
#pragma unroll
            for (int r = 0; r < TKG; ++r) { cv[g * TKG + r] = v4[r]; ci[g * TKG + r] = i4[r]; }
        }

        float v8[TOPK]; int p8[TOPK];
#pragma unroll
        for (int k = 0; k < TOPK; ++k) { v8[k] = -3.0e38f; p8[k] = 0; }
        for (int p = 0; p < NGROUP * TKG; ++p) {
            const float v = cv[p];
            if (v > v8[TOPK - 1]) {             // strict > : stable by candidate pos
                int q = TOPK - 1;
                while (q > 0 && v > v8[q - 1]) {
                    v8[q] = v8[q - 1]; p8[q] = p8[q - 1]; --q;
                }
                v8[q] = v; p8[q] = p;
            }
        }

        float w8[TOPK]; float ssum = 0.f;
#pragma unroll
        for (int k = 0; k < TOPK; ++k) {
            w8[k] = expf(v8[k] - v8[0]);
            ssum += w8[k];
        }

        const size_t row = (size_t)(t0 + t) * TOPK;
#pragma unroll
        for (int k = 0; k < TOPK; ++k) {
            const int pos = p8[k];
            const int ex  = (pos >> 2) * GSZ + ci[pos];
            out[row + k] = (float)ex;
            out[(size_t)T * TOPK + row + k] = w8[k] / ssum;
            atomicAdd(&cnt_ws[ex], 1);
        }

        float dsum = 0.f;
        for (int e2 = 0; e2 < NEXP; ++e2)
            dsum += expf(pool[t * LGSTR + e2] - gmax);
        dmax[t] = gmax;
        den[t]  = dsum;
    }
    __syncthreads();

    // ---- per-expert partial sum of probs over this block's tokens ----
    double part = 0.0;
#pragma unroll
    for (int t = 0; t < TM; ++t)
        part += (double)(expf(pool[t * LGSTR + tid] - dmax[t]) / den[t]);
    atomicAdd(&S_ws[tid], part);
}

// ---------------- tiny loss-finalize kernel ----------------
__global__ __launch_bounds__(256) void moe_gate_loss(
    const double* __restrict__ S_ws, const int* __restrict__ cnt_ws,
    float* __restrict__ out, int T)
{
    __shared__ double red[NEXP];
    const int e = threadIdx.x;
    const double S = S_ws[e];
    const double c = (double)cnt_ws[e];
    const double Td = (double)T;
    const double aux = (c / Td) * (S / Td);
    double z = log(S); z *= z;

    red[e] = aux; __syncthreads();
    for (int s = 128; s > 0; s >>= 1) { if (e < s) red[e] += red[e + s]; __syncthreads(); }
    const double auxsum = red[0];
    __syncthreads();
    red[e] = z; __syncthreads();
    for (int s = 128; s > 0; s >>= 1) { if (e < s) red[e] += red[e + s]; __syncthreads(); }
    if (e == 0)
        out[(size_t)T * TOPK * 2] = (float)(auxsum * 1.0e-3 + (red[0] / (double)NEXP) * 1.0e-4);
}

extern "C" void kernel_launch(void* const* d_in, const int* in_sizes, int n_in,
                              void* d_out, int out_size, void* d_ws, size_t ws_size,
                              hipStream_t stream)
{
    const float* X = (const float*)d_in[0];
    const float* W = (const float*)d_in[1];
    float* out = (float*)d_out;
    const int T = in_sizes[0] / HIDDEN;   // 16384

    double* S_ws   = (double*)d_ws;
    int*    cnt_ws = (int*)((char*)d_ws + NEXP * sizeof(double));

    hipMemsetAsync(d_ws, 0, NEXP * (sizeof(double) + sizeof(int)), stream);

    moe_gate_main<<<dim3(T / TM), dim3(256), 0, stream>>>(X, W, out, S_ws, cnt_ws, T);
    moe_gate_loss<<<dim3(1), dim3(256), 0, stream>>>(S_ws, cnt_ws, out, T);
}

// Round 11
// 682.296 us; speedup vs baseline: 1.1213x; 1.1213x over previous
//
#include <hip/hip_runtime.h>
#include <math.h>

#define HIDDEN  2048
#define NEXP    256
#define TOPK    8
#define NGROUP  8
#define TKG     4
#define GSZ     32
#define TM      16                 // tokens per block (r11: halved -> 4 blocks/CU)
#define KC      32                 // k-chunk (two 16-elem SSE groups)
#define NCHUNK  (HIDDEN / KC)      // 64
#define LGSTR   (NEXP + 2)         // logits row stride in pool

// Bit-exact emulation of numpy c_einsum's f32 dot kernel (SSE baseline):
//   - 4 lane-chains (k mod 4), mul/add separately rounded (no FMA)
//   - 16-elem groups ascending; within a group float4s accumulated reversed
//   - final combine (A0+A1)+(A2+A3)
// Per-(token,expert) op sequence identical to the passing r3 kernel.
// r11 change: TM 32->16, Ti 8->4 (acc 64 floats), grid 1024 = 4 blocks/CU.
// Rationale (r3 vs r5 evidence): duration tracks the number of INDEPENDENT
// barrier groups per CU, not wave occupancy. 4 blocks/CU = 4 groups; each
// block's stage->barrier drain hides under another block's MAC.
// Register law (6 failures): acc + <=8 transient float4, (256,N) keeping
// compiler cap at 128 VGPR, no values held across the MAC section.
__global__ __launch_bounds__(256, 4) void moe_gate_main(
    const float* __restrict__ X,      // [T, HIDDEN]
    const float* __restrict__ W,      // [NEXP, HIDDEN]
    float* __restrict__ out,          // [T*8 idx][T*8 w][1 loss]
    double* __restrict__ S_ws,        // [NEXP]
    int* __restrict__ cnt_ws,         // [NEXP]
    int T)
{
#pragma clang fp contract(off)
    __shared__ __align__(16) float xs[TM][KC];          // 2 KB
    __shared__ __align__(16) float pool[NEXP * KC];     // 32 KB: W tile; logits overlay (16*258 fits)
    __shared__ float dmax[TM];
    __shared__ float den[TM];

    const int tid = threadIdx.x;
    const int tg  = tid >> 6;        // wave id -> token quartet (wave-uniform)
    const int exq = tid & 63;        // expert base lane
    const int t0  = blockIdx.x * TM;
    const int swz = exq & 7;

    float4 acc[4][4];                // [token][expert-quad], 64 floats
#pragma unroll
    for (int i = 0; i < 4; ++i)
#pragma unroll
        for (int j = 0; j < 4; ++j) acc[i][j] = make_float4(0.f, 0.f, 0.f, 0.f);

    for (int c = 0; c < NCHUNK; ++c) {
        const int k0 = c * KC;
        __syncthreads();                 // previous chunk's tiles fully consumed
        // stage X chunk [16 tokens][32 k]: threads 0..127, one float4 each
        if (tid < (TM * KC / 4)) {
            const int trow = tid >> 3, col4 = tid & 7;
            const float4 v = *(const float4*)(X + (size_t)(t0 + trow) * HIDDEN + k0 + 4 * col4);
            *(float4*)&xs[trow][4 * col4] = v;
        }
        // stage W chunk [256 experts][32 k]: 8 float4 per thread (proven
        // transient batch size), XOR-swizzled 16B columns
#pragma unroll
        for (int it = 0; it < 8; ++it) {
            const int f4  = it * 256 + tid;
            const int row = f4 >> 3, col4 = f4 & 7;
            const float4 v = *(const float4*)(W + (size_t)row * HIDDEN + k0 + 4 * col4);
            *(float4*)&pool[row * KC + ((col4 ^ (row & 7)) * 4)] = v;
        }
        __syncthreads();
        // two 16-elem groups, vectors reversed within each (SSE chain order)
#pragma unroll
        for (int blk = 0; blk < 2; ++blk) {
#pragma unroll
            for (int vv = 3; vv >= 0; --vv) {
                const int k4 = blk * 4 + vv;
                const int sc = (k4 ^ swz) * 4;
                float4 wv[4];
#pragma unroll
                for (int j = 0; j < 4; ++j)
                    wv[j] = *(const float4*)&pool[(exq + 64 * j) * KC + sc];
#pragma unroll
                for (int i = 0; i < 4; ++i) {
                    const float4 xv = *(const float4*)&xs[tg * 4 + i][4 * k4];   // broadcast
#pragma unroll
                    for (int j = 0; j < 4; ++j) {
                        // ascending k within each mod-4 chain -- DO NOT reorder
                        acc[i][j].x = __fadd_rn(acc[i][j].x, __fmul_rn(xv.x, wv[j].x));
                        acc[i][j].y = __fadd_rn(acc[i][j].y, __fmul_rn(xv.y, wv[j].y));
                        acc[i][j].z = __fadd_rn(acc[i][j].z, __fmul_rn(xv.z, wv[j].z));
                        acc[i][j].w = __fadd_rn(acc[i][j].w, __fmul_rn(xv.w, wv[j].w));
                    }
                }
            }
        }
    }

    __syncthreads();   // all W-tile reads done; pool becomes the logits buffer
#pragma unroll
    for (int i = 0; i < 4; ++i)
#pragma unroll
        for (int j = 0; j < 4; ++j) {
            const float4 a = acc[i][j];
            // SSE3 hadd x2: (A0+A1)+(A2+A3)
            pool[(tg * 4 + i) * LGSTR + exq + 64 * j] =
                __fadd_rn(__fadd_rn(a.x, a.y), __fadd_rn(a.z, a.w));
        }
    __syncthreads();

    // ---- per-token selection: grouped top-4, global top-8, softmax weights ----
    if (tid < TM) {
        const int t = tid;
        float cv[NGROUP * TKG];
        int   ci[NGROUP * TKG];
        float gmax = -3.0e38f;

        for (int g = 0; g < NGROUP; ++g) {
            float v4[TKG] = { -3.0e38f, -3.0e38f, -3.0e38f, -3.0e38f };
            int   i4[TKG] = { 0, 0, 0, 0 };
            for (int jj = 0; jj < GSZ; ++jj) {
                const float v = pool[t * LGSTR + g * GSZ + jj];
                if (v > gmax) gmax = v;
                if (v > v4[TKG - 1]) {          // strict > : stable (lower idx first)
                    int q = TKG - 1;
                    while (q > 0 && v > v4[q - 1]) {
                        v4[q] = v4[q - 1]; i4[q] = i4[q - 1]; --q;
                    }
                    v4[q] = v; i4[q] = jj;
                }
            }
#pragma unroll
            for (int r = 0; r < TKG; ++r) { cv[g * TKG + r] = v4[r]; ci[g * TKG + r] = i4[r]; }
        }

        float v8[TOPK]; int p8[TOPK];
#pragma unroll
        for (int k = 0; k < TOPK; ++k) { v8[k] = -3.0e38f; p8[k] = 0; }
        for (int p = 0; p < NGROUP * TKG; ++p) {
            const float v = cv[p];
            if (v > v8[TOPK - 1]) {             // strict > : stable by candidate pos
                int q = TOPK - 1;
                while (q > 0 && v > v8[q - 1]) {
                    v8[q] = v8[q - 1]; p8[q] = p8[q - 1]; --q;
                }
                v8[q] = v; p8[q] = p;
            }
        }

        float w8[TOPK]; float ssum = 0.f;
#pragma unroll
        for (int k = 0; k < TOPK; ++k) {
            w8[k] = expf(v8[k] - v8[0]);
            ssum += w8[k];
        }

        const size_t row = (size_t)(t0 + t) * TOPK;
#pragma unroll
        for (int k = 0; k < TOPK; ++k) {
            const int pos = p8[k];
            const int ex  = (pos >> 2) * GSZ + ci[pos];
            out[row + k] = (float)ex;
            out[(size_t)T * TOPK + row + k] = w8[k] / ssum;
            atomicAdd(&cnt_ws[ex], 1);
        }

        float dsum = 0.f;
        for (int e2 = 0; e2 < NEXP; ++e2)
            dsum += expf(pool[t * LGSTR + e2] - gmax);
        dmax[t] = gmax;
        den[t]  = dsum;
    }
    __syncthreads();

    // ---- per-expert partial sum of probs over this block's tokens ----
    double part = 0.0;
#pragma unroll
    for (int t = 0; t < TM; ++t)
        part += (double)(expf(pool[t * LGSTR + tid] - dmax[t]) / den[t]);
    atomicAdd(&S_ws[tid], part);
}

// ---------------- tiny loss-finalize kernel ----------------
__global__ __launch_bounds__(256) void moe_gate_loss(
    const double* __restrict__ S_ws, const int* __restrict__ cnt_ws,
    float* __restrict__ out, int T)
{
    __shared__ double red[NEXP];
    const int e = threadIdx.x;
    const double S = S_ws[e];
    const double c = (double)cnt_ws[e];
    const double Td = (double)T;
    const double aux = (c / Td) * (S / Td);
    double z = log(S); z *= z;

    red[e] = aux; __syncthreads();
    for (int s = 128; s > 0; s >>= 1) { if (e < s) red[e] += red[e + s]; __syncthreads(); }
    const double auxsum = red[0];
    __syncthreads();
    red[e] = z; __syncthreads();
    for (int s = 128; s > 0; s >>= 1) { if (e < s) red[e] += red[e + s]; __syncthreads(); }
    if (e == 0)
        out[(size_t)T * TOPK * 2] = (float)(auxsum * 1.0e-3 + (red[0] / (double)NEXP) * 1.0e-4);
}

extern "C" void kernel_launch(void* const* d_in, const int* in_sizes, int n_in,
                              void* d_out, int out_size, void* d_ws, size_t ws_size,
                              hipStream_t stream)
{
    const float* X = (const float*)d_in[0];
    const float* W = (const float*)d_in[1];
    float* out = (float*)d_out;
    const int T = in_sizes[0] / HIDDEN;   // 16384

    double* S_ws   = (double*)d_ws;
    int*    cnt_ws = (int*)((char*)d_ws + NEXP * sizeof(double));

    hipMemsetAsync(d_ws, 0, NEXP * (sizeof(double) + sizeof(int)), stream);

    moe_gate_main<<<dim3(T / TM), dim3(256), 0, stream>>>(X, W, out, S_ws, cnt_ws, T);
    moe_gate_loss<<<dim3(1), dim3(256), 0, stream>>>(S_ws, cnt_ws, out, T);
}